// Round 3
// baseline (456.248 us; speedup 1.0000x reference)
//
#include <hip/hip_runtime.h>
#include <hip/hip_bf16.h>

// SplitMLP: B=128, C=16, V=32, H=64, O=4, G=10000
// 8 consecutive groups per block (grid=1250); wave w owns batch rows [32w,32w+32)
// for all 8 groups. Per-group: fc1 via mfma_f32_16x16x32_bf16 (A=[day|items|0]),
// wave-local LDS transpose of relu(h), fc2 as y^T = W2 @ h^T.
// y held for 4 groups -> one 64B contiguous store burst per lane (full cache line).
// All global loads hoisted to the top of each group iteration (latency hiding).

typedef __bf16 v8bf __attribute__((ext_vector_type(8)));
typedef float  v4f  __attribute__((ext_vector_type(4)));

#define B_   128
#define C_   16
#define V_   32
#define H_   64
#define O_   4
#define G_   10000
#define GPB  8
#define HS   104  // Hbuf row stride (bf16): 208B, 16B-aligned, ~2-way banks (free)

__device__ __forceinline__ v8bf cvt8(float4 lo, float4 hi) {
  v8bf r;
  r[0] = (__bf16)lo.x; r[1] = (__bf16)lo.y; r[2] = (__bf16)lo.z; r[3] = (__bf16)lo.w;
  r[4] = (__bf16)hi.x; r[5] = (__bf16)hi.y; r[6] = (__bf16)hi.z; r[7] = (__bf16)hi.w;
  return r;
}

__global__ __launch_bounds__(256, 4)
void splitmlp_kernel(const float* __restrict__ day,
                     const float* __restrict__ items,
                     const float* __restrict__ W1d,
                     const float* __restrict__ W1v,
                     const float* __restrict__ b1,
                     const float* __restrict__ W2,
                     const float* __restrict__ b2,
                     float* __restrict__ out) {
  __shared__ __bf16 Hbuf[B_ * HS];   // 26,624 B

  const int t    = threadIdx.x;
  const int g0   = blockIdx.x * GPB;
  const int w    = t >> 6;
  const int lane = t & 63;
  const int c    = lane & 15;
  const int q    = lane >> 4;
  const int r0   = w * 32;
  const int bA0  = r0 + c;
  const int bA1  = bA0 + 16;

  v8bf zf;
#pragma unroll
  for (int i = 0; i < 8; ++i) zf[i] = (__bf16)0.0f;
  v4f zero = {0.f, 0.f, 0.f, 0.f};

  float4 o0[4], o1[4];   // y window (valid on q==0 lanes)

#pragma unroll
  for (int gi = 0; gi < GPB; ++gi) {
    const int g = g0 + gi;
    const float* W1dg = W1d + (size_t)g * (H_ * C_);
    const float* W1vg = W1v + (size_t)g * (H_ * V_);
    const float* W2g  = W2  + (size_t)g * (O_ * H_);
    const size_t gV   = (size_t)g * V_;

    // ---------------- hoisted global loads (fp32) ----------------
    float4 Af[2][2][2];   // [row01][kt][half]
    float4 Bf[2][4][2];   // [kt][n][half]
    float4 Wf[2][2];      // [kt][half]
#pragma unroll
    for (int kt = 0; kt < 2; ++kt) {
      const int  k0    = kt * 32 + q * 8;
      const bool isday = (k0 < 16);
      const bool valid = (k0 < 48);
      const float* pa0 = isday ? (day + bA0 * C_ + k0)
                       : valid ? (items + (size_t)bA0 * (G_ * V_) + gV + (k0 - 16))
                               : day;
      const float* pa1 = isday ? (day + bA1 * C_ + k0)
                       : valid ? (items + (size_t)bA1 * (G_ * V_) + gV + (k0 - 16))
                               : day;
      Af[0][kt][0] = reinterpret_cast<const float4*>(pa0)[0];
      Af[0][kt][1] = reinterpret_cast<const float4*>(pa0)[1];
      Af[1][kt][0] = reinterpret_cast<const float4*>(pa1)[0];
      Af[1][kt][1] = reinterpret_cast<const float4*>(pa1)[1];
#pragma unroll
      for (int n = 0; n < 4; ++n) {
        const int h = n * 16 + c;
        const float* pw = isday ? (W1dg + h * C_ + k0)
                        : valid ? (W1vg + h * V_ + (k0 - 16))
                                : day;
        Bf[kt][n][0] = reinterpret_cast<const float4*>(pw)[0];
        Bf[kt][n][1] = reinterpret_cast<const float4*>(pw)[1];
      }
      const float* pw2 = (c < O_) ? (W2g + c * H_ + k0) : day;
      Wf[kt][0] = reinterpret_cast<const float4*>(pw2)[0];
      Wf[kt][1] = reinterpret_cast<const float4*>(pw2)[1];
    }
    float bias[4];
#pragma unroll
    for (int n = 0; n < 4; ++n) bias[n] = b1[(size_t)g * H_ + n * 16 + c];
    const float4 b2v = *reinterpret_cast<const float4*>(b2 + (size_t)g * O_);

    // ---------------- convert to bf16 fragments ----------------
    v8bf a[2][2], bw[2][4], wf[2];
#pragma unroll
    for (int kt = 0; kt < 2; ++kt) {
      const int  k0    = kt * 32 + q * 8;
      const bool valid = (k0 < 48);
      a[0][kt] = valid ? cvt8(Af[0][kt][0], Af[0][kt][1]) : zf;
      a[1][kt] = valid ? cvt8(Af[1][kt][0], Af[1][kt][1]) : zf;
#pragma unroll
      for (int n = 0; n < 4; ++n) bw[kt][n] = cvt8(Bf[kt][n][0], Bf[kt][n][1]);
      wf[kt] = (c < O_) ? cvt8(Wf[kt][0], Wf[kt][1]) : zf;
    }

    // ---------------- fc1 ----------------
    v4f acc[2][4];
#pragma unroll
    for (int m = 0; m < 2; ++m)
#pragma unroll
      for (int n = 0; n < 4; ++n) acc[m][n] = zero;
#pragma unroll
    for (int kt = 0; kt < 2; ++kt)
#pragma unroll
      for (int n = 0; n < 4; ++n) {
        acc[0][n] = __builtin_amdgcn_mfma_f32_16x16x32_bf16(a[0][kt], bw[kt][n], acc[0][n], 0, 0, 0);
        acc[1][n] = __builtin_amdgcn_mfma_f32_16x16x32_bf16(a[1][kt], bw[kt][n], acc[1][n], 0, 0, 0);
      }

    // epilogue: +b1, ReLU -> Hbuf (wave-local rows; no barrier needed)
#pragma unroll
    for (int n = 0; n < 4; ++n)
#pragma unroll
      for (int m = 0; m < 2; ++m)
#pragma unroll
        for (int r = 0; r < 4; ++r) {
          float v = fmaxf(acc[m][n][r] + bias[n], 0.0f);
          Hbuf[(r0 + m * 16 + q * 4 + r) * HS + n * 16 + c] = (__bf16)v;
        }

    // ---------------- fc2: y^T = W2(pad16) @ h^T ----------------
    v4f y0 = zero, y1 = zero;
#pragma unroll
    for (int kt = 0; kt < 2; ++kt) {
      const int k0 = kt * 32 + q * 8;
      v8bf h0 = *reinterpret_cast<const v8bf*>(&Hbuf[(r0 + c) * HS + k0]);
      v8bf h1 = *reinterpret_cast<const v8bf*>(&Hbuf[(r0 + 16 + c) * HS + k0]);
      y0 = __builtin_amdgcn_mfma_f32_16x16x32_bf16(wf[kt], h0, y0, 0, 0, 0);
      y1 = __builtin_amdgcn_mfma_f32_16x16x32_bf16(wf[kt], h1, y1, 0, 0, 0);
    }
    const int s = gi & 3;
    o0[s].x = y0[0] + b2v.x; o0[s].y = y0[1] + b2v.y; o0[s].z = y0[2] + b2v.z; o0[s].w = y0[3] + b2v.w;
    o1[s].x = y1[0] + b2v.x; o1[s].y = y1[1] + b2v.y; o1[s].z = y1[2] + b2v.z; o1[s].w = y1[3] + b2v.w;

    // every 4 groups: one 64B contiguous burst per lane (full cache line)
    if (s == 3 && q == 0) {
      const size_t gbase = (size_t)(g0 + (gi & ~3)) * O_;
      float* p0 = out + (size_t)(r0 + c) * (G_ * O_) + gbase;
      float* p1 = out + (size_t)(r0 + 16 + c) * (G_ * O_) + gbase;
#pragma unroll
      for (int j = 0; j < 4; ++j) reinterpret_cast<float4*>(p0)[j] = o0[j];
#pragma unroll
      for (int j = 0; j < 4; ++j) reinterpret_cast<float4*>(p1)[j] = o1[j];
    }
  }
}

extern "C" void kernel_launch(void* const* d_in, const int* in_sizes, int n_in,
                              void* d_out, int out_size, void* d_ws, size_t ws_size,
                              hipStream_t stream) {
  const float* day   = (const float*)d_in[0];
  const float* items = (const float*)d_in[1];
  const float* W1d   = (const float*)d_in[2];
  const float* W1v   = (const float*)d_in[3];
  const float* b1    = (const float*)d_in[4];
  const float* W2    = (const float*)d_in[5];
  const float* b2    = (const float*)d_in[6];
  float* out = (float*)d_out;
  splitmlp_kernel<<<(G_ + GPB - 1) / GPB, 256, 0, stream>>>(day, items, W1d, W1v, b1, W2, b2, out);
}

// Round 4
// 352.757 us; speedup vs baseline: 1.2934x; 1.2934x over previous
//
#include <hip/hip_runtime.h>
#include <hip/hip_bf16.h>

// SplitMLP: B=128, C=16, V=32, H=64, O=4, G=10000
// Block = 256 thr / 4 waves, GPB=4 consecutive groups (grid 2500).
// fc1 flipped: h^T = W1 @ A^T  (M=hidden 64, N=batch, K=48->64 w/ zeroed regs).
//   - W1 staged in LDS once/group (coalesced, shared by 4 waves), register-prefetched
//     one group ahead so global latency overlaps previous group's compute.
//   - A^T B-frags read DIRECT from global: lane(c,q) <- A[batch c][8q..8q+8) =
//     16 full 128B item lines per instruction pair (minimal TCP line-touches).
// fc2: y^T = W2 @ h^T; h^T round-trips wave-private LDS (packed b64 writes).
// Output accumulated in LDS Ybuf, stored as full 64B lines (no partial-line RMW).

typedef __bf16 v8bf __attribute__((ext_vector_type(8)));
typedef __bf16 v4bf __attribute__((ext_vector_type(4)));
typedef float  v4f  __attribute__((ext_vector_type(4)));

#define B_   128
#define C_   16
#define V_   32
#define H_   64
#define O_   4
#define G_   10000
#define GPB  4
#define WS_  56   // W1s stride (elems): 112B = 16B-aligned rows, 2-way banks (free)
#define HS_  72   // Hb stride: 144B = 16B-aligned, 2-way banks
#define YS_  20   // Ybuf stride (f32): 80B, float4-aligned

__device__ __forceinline__ v4bf cvt4(float4 f) {
  v4bf r;
  r[0] = (__bf16)f.x; r[1] = (__bf16)f.y; r[2] = (__bf16)f.z; r[3] = (__bf16)f.w;
  return r;
}
__device__ __forceinline__ v8bf cvt8(float4 lo, float4 hi) {
  v8bf r;
  r[0] = (__bf16)lo.x; r[1] = (__bf16)lo.y; r[2] = (__bf16)lo.z; r[3] = (__bf16)lo.w;
  r[4] = (__bf16)hi.x; r[5] = (__bf16)hi.y; r[6] = (__bf16)hi.z; r[7] = (__bf16)hi.w;
  return r;
}
__device__ __forceinline__ v8bf gload8(const float* __restrict__ p) {
  const float4* p4 = reinterpret_cast<const float4*>(p);
  return cvt8(p4[0], p4[1]);
}

__global__ __launch_bounds__(256, 4)
void splitmlp_kernel(const float* __restrict__ day,
                     const float* __restrict__ items,
                     const float* __restrict__ W1d,
                     const float* __restrict__ W1v,
                     const float* __restrict__ b1,
                     const float* __restrict__ W2,
                     const float* __restrict__ b2,
                     float* __restrict__ out) {
  __shared__ __bf16 W1s[H_ * WS_];        //  7,168 B  [h][k 0..48)
  __shared__ __bf16 Hb[4][32 * HS_];      // 18,432 B  per-wave [batch32][hidden64]
  __shared__ float  Yb[B_ * YS_];         // 10,240 B  [b][16 used]

  const int t    = threadIdx.x;
  const int g0   = blockIdx.x * GPB;
  const int w    = t >> 6;
  const int lane = t & 63;
  const int c    = lane & 15;
  const int q    = lane >> 4;
  const int wbase = w * 32;

  v8bf zf;
#pragma unroll
  for (int i = 0; i < 8; ++i) zf[i] = (__bf16)0.0f;
  const v4f zero = {0.f, 0.f, 0.f, 0.f};

  // ---- W1 register prefetch (group g0) ----
  float4 pd, pv0, pv1;
  {
    const float* W1dg = W1d + (size_t)g0 * (H_ * C_);
    const float* W1vg = W1v + (size_t)g0 * (H_ * V_);
    pd  = reinterpret_cast<const float4*>(W1dg)[t];
    pv0 = reinterpret_cast<const float4*>(W1vg)[t];
    pv1 = reinterpret_cast<const float4*>(W1vg)[t + 256];
  }

#pragma unroll 1
  for (int gi = 0; gi < GPB; ++gi) {
    const int g = g0 + gi;

    __syncthreads();   // all waves done reading W1s of previous group
    // stage W1(g) from prefetch regs (packed b64 writes)
    {
      const int hd = t >> 2, kd = (t & 3) << 2;
      *reinterpret_cast<v4bf*>(&W1s[hd * WS_ + kd]) = cvt4(pd);
      const int hv0 = t >> 3, kv0 = C_ + ((t & 7) << 2);
      *reinterpret_cast<v4bf*>(&W1s[hv0 * WS_ + kv0]) = cvt4(pv0);
      const int i2 = t + 256;
      const int hv1 = i2 >> 3, kv1 = C_ + ((i2 & 7) << 2);
      *reinterpret_cast<v4bf*>(&W1s[hv1 * WS_ + kv1]) = cvt4(pv1);
    }
    // issue next group's W1 prefetch (latency overlaps this group's compute)
    if (gi < GPB - 1) {
      const float* W1dn = W1d + (size_t)(g + 1) * (H_ * C_);
      const float* W1vn = W1v + (size_t)(g + 1) * (H_ * V_);
      pd  = reinterpret_cast<const float4*>(W1dn)[t];
      pv0 = reinterpret_cast<const float4*>(W1vn)[t];
      pv1 = reinterpret_cast<const float4*>(W1vn)[t + 256];
    }
    __syncthreads();   // W1s(g) visible

    // ---- A^T B-frags direct from global ----
    // lane(c,q): A[batch b][k]: k<16 day, 16..47 items, 48..63 zero
    v8bf bfrag[2][2];
#pragma unroll
    for (int nb = 0; nb < 2; ++nb) {
      const int b = wbase + nb * 16 + c;
      const float* pit = items + (size_t)b * (G_ * V_) + (size_t)g * V_;
      const float* p0 = (q < 2) ? (day + b * C_ + q * 8) : (pit + (q - 2) * 8);
      bfrag[nb][0] = gload8(p0);
      bfrag[nb][1] = (q < 2) ? gload8(pit + 16 + q * 8) : zf;
    }

    // ---- W1 A-frags from LDS ----
    v8bf wfrag[4][2];
#pragma unroll
    for (int m = 0; m < 4; ++m) {
      const int row = (m * 16 + c) * WS_;
      wfrag[m][0] = *reinterpret_cast<const v8bf*>(&W1s[row + q * 8]);
      wfrag[m][1] = (q < 2) ? *reinterpret_cast<const v8bf*>(&W1s[row + 32 + q * 8]) : zf;
    }

    // ---- fc1 MFMA: D[hidden][batch] ----
    v4f acc[4][2];
#pragma unroll
    for (int m = 0; m < 4; ++m)
#pragma unroll
      for (int nb = 0; nb < 2; ++nb) acc[m][nb] = zero;
#pragma unroll
    for (int m = 0; m < 4; ++m)
#pragma unroll
      for (int nb = 0; nb < 2; ++nb) {
        acc[m][nb] = __builtin_amdgcn_mfma_f32_16x16x32_bf16(wfrag[m][0], bfrag[nb][0], acc[m][nb], 0, 0, 0);
        acc[m][nb] = __builtin_amdgcn_mfma_f32_16x16x32_bf16(wfrag[m][1], bfrag[nb][1], acc[m][nb], 0, 0, 0);
      }

    // ---- epilogue: +b1, ReLU, packed b64 -> Hb (wave-private) ----
    // lane(c,q) reg r = h^T[hidden m*16+q*4+r][batch wbase+nb*16+c]
#pragma unroll
    for (int m = 0; m < 4; ++m) {
      const float4 bb = *reinterpret_cast<const float4*>(b1 + (size_t)g * H_ + m * 16 + q * 4);
#pragma unroll
      for (int nb = 0; nb < 2; ++nb) {
        v4bf hv;
        hv[0] = (__bf16)fmaxf(acc[m][nb][0] + bb.x, 0.f);
        hv[1] = (__bf16)fmaxf(acc[m][nb][1] + bb.y, 0.f);
        hv[2] = (__bf16)fmaxf(acc[m][nb][2] + bb.z, 0.f);
        hv[3] = (__bf16)fmaxf(acc[m][nb][3] + bb.w, 0.f);
        *reinterpret_cast<v4bf*>(&Hb[w][(nb * 16 + c) * HS_ + m * 16 + q * 4]) = hv;
      }
    }

    // ---- fc2: y^T = W2(pad16) @ h^T ----
    v4f y[2] = {zero, zero};
#pragma unroll
    for (int kt = 0; kt < 2; ++kt) {
      const float* pw2 = W2 + (size_t)g * (O_ * H_) + c * H_ + kt * 32 + q * 8;
      v8bf w2f = (c < O_) ? gload8(pw2) : zf;
#pragma unroll
      for (int nb = 0; nb < 2; ++nb) {
        v8bf hf = *reinterpret_cast<const v8bf*>(&Hb[w][(nb * 16 + c) * HS_ + kt * 32 + q * 8]);
        y[nb] = __builtin_amdgcn_mfma_f32_16x16x32_bf16(w2f, hf, y[nb], 0, 0, 0);
      }
    }

    // ---- y -> Ybuf (q==0 lanes hold o=0..3 as regs r) ----
    if (q == 0) {
      const float4 b2v = *reinterpret_cast<const float4*>(b2 + (size_t)g * O_);
#pragma unroll
      for (int nb = 0; nb < 2; ++nb) {
        const int b = wbase + nb * 16 + c;
        float4 o;
        o.x = y[nb][0] + b2v.x;
        o.y = y[nb][1] + b2v.y;
        o.z = y[nb][2] + b2v.z;
        o.w = y[nb][3] + b2v.w;
        *reinterpret_cast<float4*>(&Yb[b * YS_ + gi * 4]) = o;
      }
    }
  }

  __syncthreads();
  // cooperative output store: full 64B line per 4-lane cluster, no partial-line RMW
#pragma unroll
  for (int i = t; i < 512; i += 256) {
    const int b = i >> 2, c4 = i & 3;
    const float4 v = *reinterpret_cast<const float4*>(&Yb[b * YS_ + c4 * 4]);
    *reinterpret_cast<float4*>(out + (size_t)b * (G_ * O_) + (size_t)g0 * O_ + c4 * 4) = v;
  }
}

extern "C" void kernel_launch(void* const* d_in, const int* in_sizes, int n_in,
                              void* d_out, int out_size, void* d_ws, size_t ws_size,
                              hipStream_t stream) {
  const float* day   = (const float*)d_in[0];
  const float* items = (const float*)d_in[1];
  const float* W1d   = (const float*)d_in[2];
  const float* W1v   = (const float*)d_in[3];
  const float* b1    = (const float*)d_in[4];
  const float* W2    = (const float*)d_in[5];
  const float* b2    = (const float*)d_in[6];
  float* out = (float*)d_out;
  splitmlp_kernel<<<G_ / GPB, 256, 0, stream>>>(day, items, W1d, W1v, b1, W2, b2, out);
}